// Round 1
// baseline (127.880 us; speedup 1.0000x reference)
//
#include <hip/hip_runtime.h>
#include <hip/hip_bf16.h>
#include <cstdint>
#include <cstddef>

// Problem constants (fixed by the reference: anchor/positive [4096,512] f32, labels [4096] i32)
constexpr int BN = 4096;   // batch
constexpr int DN = 512;    // feature dim
constexpr float MARGIN = 0.2f;
constexpr uint32_t INF_U = 0x7f800000u;   // +inf bit pattern; positive-float order == uint order

typedef __attribute__((ext_vector_type(8))) short short8;     // 8 bf16 = 4 VGPRs (MFMA A/B frag)
typedef __attribute__((ext_vector_type(4))) float float4v;    // MFMA C/D frag

#define AS1(p) ((const __attribute__((address_space(1))) void*)(p))
#define AS3(p) ((__attribute__((address_space(3))) void*)(p))

// ---------------------------------------------------------------------------
// Kernel 1: per-row stats + bf16 cast of anchor + init of min arrays.
// One wave per row (4 rows / 256-thread block). Lane l owns elems [8l, 8l+8).
// ---------------------------------------------------------------------------
__global__ __launch_bounds__(256) void prep_kernel(
    const float* __restrict__ anchor,
    const float* __restrict__ positive,
    uint16_t* __restrict__ Abf,        // [BN][DN] bf16 bits
    float* __restrict__ sqn,           // [BN] ||a_i||^2
    float* __restrict__ dap,           // [BN] squared anchor-positive dist
    uint32_t* __restrict__ min_all,    // [BN] +inf-initialized
    uint32_t* __restrict__ min_larger) // [BN] +inf-initialized
{
    const int tid  = threadIdx.x;
    const int wave = tid >> 6;
    const int lane = tid & 63;
    const int row  = blockIdx.x * 4 + wave;

    const float4* arow = (const float4*)(anchor   + (size_t)row * DN);
    const float4* prow = (const float4*)(positive + (size_t)row * DN);

    float4 av0 = arow[lane * 2 + 0], av1 = arow[lane * 2 + 1];
    float4 pv0 = prow[lane * 2 + 0], pv1 = prow[lane * 2 + 1];

    float a[8] = {av0.x, av0.y, av0.z, av0.w, av1.x, av1.y, av1.z, av1.w};
    float p[8] = {pv0.x, pv0.y, pv0.z, pv0.w, pv1.x, pv1.y, pv1.z, pv1.w};

    float s = 0.f, d = 0.f;
    union { uint16_t u[8]; uint4 v; } pk;
    #pragma unroll
    for (int i = 0; i < 8; ++i) {
        s += a[i] * a[i];
        float dx = a[i] - p[i];
        d += dx * dx;
        uint32_t ub = __float_as_uint(a[i]);               // RNE f32 -> bf16
        pk.u[i] = (uint16_t)((ub + 0x7fffu + ((ub >> 16) & 1u)) >> 16);
    }

    ((uint4*)(Abf + (size_t)row * DN))[lane] = pk.v;       // 16B coalesced store

    #pragma unroll
    for (int off = 32; off; off >>= 1) {
        s += __shfl_xor(s, off);
        d += __shfl_xor(d, off);
    }
    if (lane == 0) {
        sqn[row] = s;
        dap[row] = d;
        min_all[row]    = INF_U;
        min_larger[row] = INF_U;
    }
}

// ---------------------------------------------------------------------------
// Kernel 2: S = A·A^T in 128x128 tiles (bf16 MFMA 16x16x32), fused epilogue:
// pd = sqrt(max(sq_i + sq_j - 2*S, 0)), masked row-mins -> atomicMin (uint).
// 256 threads = 4 waves in a 2x2 grid; each wave computes 64x64 via 4x4 MFMAs.
// ---------------------------------------------------------------------------
__global__ __launch_bounds__(256) void gram_kernel(
    const uint16_t* __restrict__ Abf,
    const float* __restrict__ sqn,
    const float* __restrict__ dap,
    const int* __restrict__ labels,
    uint32_t* __restrict__ min_all,
    uint32_t* __restrict__ min_larger)
{
    __shared__ uint16_t Abuf[128 * 32];   // 8 KB: i-rows tile, [row][k] row-major
    __shared__ uint16_t Bbuf[128 * 32];   // 8 KB: j-rows tile

    const int tid  = threadIdx.x;
    const int wave = tid >> 6;
    const int lane = tid & 63;
    const int wi   = wave >> 1;       // wave row in 2x2 grid
    const int wj   = wave & 1;        // wave col
    const int quad = lane >> 4;
    const int l15  = lane & 15;

    const int rowBase = blockIdx.x * 128;
    const int colBase = blockIdx.y * 128;

    float4v acc[4][4];
    #pragma unroll
    for (int i = 0; i < 4; ++i)
        #pragma unroll
        for (int j = 0; j < 4; ++j)
            acc[i][j] = (float4v){0.f, 0.f, 0.f, 0.f};

    const int ldRow   = lane >> 2;    // 0..15 : row within 16-row slab
    const int ldChunk = lane & 3;     // 0..3  : 8-elem chunk within 32-elem row

    for (int kt = 0; kt < DN / 32; ++kt) {
        const int k0 = kt * 32;
        __syncthreads();   // protect LDS from previous iteration's readers
        #pragma unroll
        for (int p = 0; p < 2; ++p) {
            const int r = p * 64 + wave * 16;   // wave-uniform 16-row slab
            const uint16_t* ga = Abf + (size_t)(rowBase + r + ldRow) * DN + k0 + ldChunk * 8;
            __builtin_amdgcn_global_load_lds(AS1(ga), AS3(Abuf + r * 32), 16, 0, 0);
            const uint16_t* gb = Abf + (size_t)(colBase + r + ldRow) * DN + k0 + ldChunk * 8;
            __builtin_amdgcn_global_load_lds(AS1(gb), AS3(Bbuf + r * 32), 16, 0, 0);
        }
        __syncthreads();   // drains vmcnt: LDS tiles ready

        short8 a_frag[4], b_frag[4];
        #pragma unroll
        for (int mi = 0; mi < 4; ++mi)
            a_frag[mi] = *(const short8*)(Abuf + (wi * 64 + mi * 16 + l15) * 32 + quad * 8);
        #pragma unroll
        for (int mj = 0; mj < 4; ++mj)
            b_frag[mj] = *(const short8*)(Bbuf + (wj * 64 + mj * 16 + l15) * 32 + quad * 8);

        #pragma unroll
        for (int mi = 0; mi < 4; ++mi)
            #pragma unroll
            for (int mj = 0; mj < 4; ++mj)
                acc[mi][mj] = __builtin_amdgcn_mfma_f32_16x16x32_bf16(
                    a_frag[mi], b_frag[mj], acc[mi][mj], 0, 0, 0);
    }

    // ---- epilogue: fused pd + masked mins ----
    const float INFF = __uint_as_float(INF_U);
    float sqj[4]; int labj[4];
    #pragma unroll
    for (int mj = 0; mj < 4; ++mj) {
        int col = colBase + wj * 64 + mj * 16 + l15;   // C/D col = lane&15
        sqj[mj]  = sqn[col];
        labj[mj] = labels[col];
    }
    #pragma unroll
    for (int mi = 0; mi < 4; ++mi) {
        #pragma unroll
        for (int r = 0; r < 4; ++r) {
            int row = rowBase + wi * 64 + mi * 16 + quad * 4 + r;  // C/D row = quad*4+reg
            float sqi  = sqn[row];
            int   li   = labels[row];
            float dapi = dap[row];
            float mAll = INFF, mLarger = INFF;
            #pragma unroll
            for (int mj = 0; mj < 4; ++mj) {
                float g  = acc[mi][mj][r];
                float d2 = sqi + sqj[mj] - 2.0f * g;
                float pd = d2 > 0.f ? sqrtf(d2) : 0.f;
                if (labj[mj] != li) {
                    mAll = fminf(mAll, pd);
                    if (pd > dapi) mLarger = fminf(mLarger, pd);
                }
            }
            // min across the 16 lanes of this quad (they share `row`, cover 64 cols)
            #pragma unroll
            for (int off = 1; off < 16; off <<= 1) {
                mAll    = fminf(mAll,    __shfl_xor(mAll, off));
                mLarger = fminf(mLarger, __shfl_xor(mLarger, off));
            }
            if (l15 == 0) {
                atomicMin(&min_all[row],    __float_as_uint(mAll));
                atomicMin(&min_larger[row], __float_as_uint(mLarger));
            }
        }
    }
}

// ---------------------------------------------------------------------------
// Kernel 3: semi-hard select + hinge + mean. One 256-thread block.
// ---------------------------------------------------------------------------
__global__ __launch_bounds__(256) void finalize_kernel(
    const float* __restrict__ dap,
    const uint32_t* __restrict__ min_all,
    const uint32_t* __restrict__ min_larger,
    float* __restrict__ out)
{
    const int tid = threadIdx.x;
    float s = 0.f;
    for (int i = tid; i < BN; i += 256) {
        uint32_t mlu = min_larger[i];
        float dan = (mlu != INF_U) ? __uint_as_float(mlu) : __uint_as_float(min_all[i]);
        float l = dap[i] - dan + MARGIN;   // -inf if no diff-label negative -> clamped to 0
        s += l > 0.f ? l : 0.f;
    }
    #pragma unroll
    for (int off = 32; off; off >>= 1) s += __shfl_xor(s, off);
    __shared__ float wsum[4];
    if ((tid & 63) == 0) wsum[tid >> 6] = s;
    __syncthreads();
    if (tid == 0) out[0] = (wsum[0] + wsum[1] + wsum[2] + wsum[3]) * (1.0f / BN);
}

// ---------------------------------------------------------------------------
extern "C" void kernel_launch(void* const* d_in, const int* in_sizes, int n_in,
                              void* d_out, int out_size, void* d_ws, size_t ws_size,
                              hipStream_t stream) {
    const float* anchor   = (const float*)d_in[0];
    const float* positive = (const float*)d_in[1];
    const int*   labels   = (const int*)d_in[2];
    float* out = (float*)d_out;

    // Workspace layout (needs ~4.26 MB)
    uint8_t* ws = (uint8_t*)d_ws;
    uint16_t* Abf       = (uint16_t*)ws;                          // 4 MB bf16 anchor
    float*    sqn       = (float*)(ws + (size_t)BN * DN * 2);     // 16 KB
    float*    dap       = sqn + BN;                               // 16 KB
    uint32_t* min_all   = (uint32_t*)(dap + BN);                  // 16 KB
    uint32_t* min_larger = min_all + BN;                          // 16 KB

    prep_kernel<<<BN / 4, 256, 0, stream>>>(anchor, positive, Abf, sqn, dap, min_all, min_larger);
    gram_kernel<<<dim3(BN / 128, BN / 128), 256, 0, stream>>>(Abf, sqn, dap, labels, min_all, min_larger);
    finalize_kernel<<<1, 256, 0, stream>>>(dap, min_all, min_larger, out);
}